// Round 7
// baseline (466.939 us; speedup 1.0000x reference)
//
#include <hip/hip_runtime.h>

typedef unsigned short u16;
typedef __bf16 bf16_t;
typedef __bf16 bf16x8 __attribute__((ext_vector_type(8)));
typedef float f32x4 __attribute__((ext_vector_type(4)));
typedef unsigned short u16x8 __attribute__((ext_vector_type(8)));
typedef unsigned short u16x4 __attribute__((ext_vector_type(4)));

#define S_LEN 2048
#define NHEAD 16
#define HD 128
#define HID 2048
#define QKV_N 6144

__device__ __forceinline__ float b2f(u16 u) {
  union { unsigned int i; float f; } x; x.i = ((unsigned int)u) << 16; return x.f;
}
__device__ __forceinline__ u16 f2b(float f) {
  bf16_t h = (bf16_t)f;
  return __builtin_bit_cast(unsigned short, h);
}

// async global->LDS, 16B per lane. lds dest must be wave-uniform; data lands at
// dest + lane*16.
__device__ __forceinline__ void gl_lds16(const u16* g, u16* l) {
  __builtin_amdgcn_global_load_lds(
      (const __attribute__((address_space(1))) unsigned int*)g,
      (__attribute__((address_space(3))) unsigned int*)l, 16, 0, 0);
}

// ---------------- dtype sniffer: 1 if fp32, 0 if bf16 ----------------
__global__ void detect_dtype_k(const void* __restrict__ x, int* __restrict__ flag) {
  __shared__ int cnt;
  if (threadIdx.x == 0) cnt = 0;
  __syncthreads();
  const u16* xu = (const u16*)x;
  int sane = 0;
  for (int i = threadIdx.x; i < 8192; i += 256) {
    int e = (xu[i] >> 7) & 0xFF;
    if (e == 0 || (e > 100 && e < 140)) sane++;
  }
  atomicAdd(&cnt, sane);
  __syncthreads();
  if (threadIdx.x == 0) *flag = (cnt < 7373) ? 1 : 0;
}

// ---------------- convert input (fp32|bf16) -> bf16 ----------------
__global__ __launch_bounds__(256) void convert_any_k(const void* __restrict__ in, u16* __restrict__ out,
                                                     const int* __restrict__ flag) {
  int i = (blockIdx.x * 256 + threadIdx.x) * 4;
  if (*flag) {
    const float4 v = *(const float4*)((const float*)in + i);
    u16x4 o = {f2b(v.x), f2b(v.y), f2b(v.z), f2b(v.w)};
    *(u16x4*)(out + i) = o;
  } else {
    *(u16x4*)(out + i) = *(const u16x4*)((const u16*)in + i);
  }
}

// ---------------- transpose [R][C] -> [C][R], (fp32|bf16) in -> bf16 out ----------------
__global__ __launch_bounds__(256) void transpose_any(const void* __restrict__ in,
                                                     u16* __restrict__ out, int R, int C,
                                                     const int* __restrict__ flag) {
  __shared__ u16 t[64][65];
  bool isf = (*flag != 0);
  int tid = threadIdx.x;
  int r0 = blockIdx.y * 64, c0 = blockIdx.x * 64;
#pragma unroll
  for (int p = 0; p < 16; ++p) {
    int e = p * 256 + tid;
    int r = e >> 6, c = e & 63;
    size_t idx = (size_t)(r0 + r) * C + (c0 + c);
    t[r][c] = isf ? f2b(((const float*)in)[idx]) : ((const u16*)in)[idx];
  }
  __syncthreads();
#pragma unroll
  for (int p = 0; p < 16; ++p) {
    int e = p * 256 + tid;
    int r = e >> 6, c = e & 63;
    out[(size_t)(c0 + r) * R + (r0 + c)] = t[c][r];
  }
}

// ---------------- RoPE cos/sin table ----------------
__global__ void rope_table_k(float* __restrict__ tab) {
  int i = blockIdx.x * 256 + threadIdx.x;
  int s = i >> 6, d = i & 63;
  float inv = expf(-(float)d * (9.210340371976184f / 64.0f));
  float ang = (float)s * inv;
  tab[s * 128 + d] = cosf(ang);
  tab[s * 128 + 64 + d] = sinf(ang);
}

// ---------------- relative bias ----------------
__global__ void build_bias_k(const void* __restrict__ table, float* __restrict__ bias,
                             const int* __restrict__ flag) {
  int i = blockIdx.x * 256 + threadIdx.x;
  int h = i >> 11, dist = i & 2047;
  int bucket;
  if (dist < 16) bucket = dist;
  else {
    int lb = (int)(logf((float)dist * 0.0625f) / 2.0794415f * 16.0f) + 16;
    bucket = lb < 31 ? lb : 31;
  }
  int ti = bucket * NHEAD + h;
  float tv = (*flag) ? ((const float*)table)[ti] : b2f(((const u16*)table)[ti]);
  bias[h * 2048 + dist] = tv;
}

// ---------------- GEMM 128x256, 4-phase, reg-pipelined, 1 barrier/phase ----------------
// C = A[M][K] * B[N][K]^T. Requires M%128==0, N%256==0, K%128==0, nwg%8==0.
// 8 waves (2M x 4N; per-wave 64x64 out), BK=64, LDS 96 KiB (sA 2x16KB, sB
// 2x32KB), st_16x32 XOR swizzle (both-sides: inverse-swizzled global source +
// swizzled ds_read offset). r4's reg-pipelined 1-barrier schedule, 16 MFMA per
// barrier preserved (full-N x M-half per phase, B held in regs).
//
// r7 change (grid quantization): schedule variants r1-r6 bracketed per-block
// util at 44-51% -- scheduling is saturated. The measured 38% avg MfmaUtil was
// 0.75x per-block util from the 384-block / 256-CU tail (makespan 2xTb, second
// half at 50% machine occupancy). 128x256 tiles -> QKV grid 32x24=768 = 3
// EXACT rounds; out-proj grid 32x8=256 = 1 exact round (also moved onto this
// kernel, replacing the m97 gemm's 2 rounds).
//
// 4 phases/iter (2 K-tiles): P1=(M0,t) P2=(M1,t) P3=(M0,t+1) P4=(M1,t+1).
// Phase = [vmcnt?; BAR; MFMA(16); stages; reads_{p+1}]. Reads at p's body are
// consumed at p+1's MFMA (>= 1 barrier in flight); MFMA precedes reads in
// program order so reg WARs (Bf overwrite at P2/P4) are pinned by deps.
// Stages all post-BAR:
//  P1: B(t+2)->buf0  (buf0-B last read prev-P4-body; BAR-P1 between)
//  P2: A(t+2)->buf0  (buf0-A last read P1-body a1; BAR-P2)
//  P3: B(t+3)->buf1  (buf1-B last read P2-body Bf; BAR-P3)
//  P4: A(t+3)->buf1  (buf1-A last read P3-body a1; BAR-P4)
// vmcnt(4) ledger (per wave; B-stage=4 loads, A-stage=2):
//  P2-pre: outstanding = B(t+1)4 + A(t+1)2 + B(t+2)4 = 10 -> drain to 4
//    completes oldest 6 = tile t+1 => buf1 ready for P2-body reads.
//  P4-pre: outstanding = B(t+2)4 + A(t+2)2 + B(t+3)4 = 10 -> drain to 4
//    completes tile t+2 => buf0 ready for P4-body reads.
// vmcnt pre-BAR => all waves' loads landed before any wave's post-BAR read.
// Prologue: 12 loads (t0: 6, t1: 6), vmcnt(6) drains t0; pre-read a0,Bf(t0).
// Tail: last P4-body reads target tile 2*nIt (k-wrapped garbage; dead regs).
template <bool F32OUT>
__global__ __launch_bounds__(512, 2) void gemm128_bt(const u16* __restrict__ A,
                                                     const u16* __restrict__ B,
                                                     void* __restrict__ Cv,
                                                     int M, int N, int K) {
  __shared__ __align__(16) u16 sA[2][8192];    // 128 x 64, 16 subtiles/buf
  __shared__ __align__(16) u16 sB[2][16384];   // 256 x 64, 32 subtiles/buf
  (void)M;
  const int tid = threadIdx.x;
  const int lane = tid & 63, w = tid >> 6;
  const int wm = w >> 2, wn = w & 3;
  const int lane16 = lane & 15, quad = lane >> 4;

  // T1: XCD-aware bijective block swizzle (nwg % 8 == 0 at both call sites)
  const int nbx = gridDim.x;
  const int nwg = nbx * gridDim.y;
  const int bid = blockIdx.y * nbx + blockIdx.x;
  const int cpx = nwg >> 3;
  const int swz = (bid & 7) * cpx + (bid >> 3);
  const int m0 = (swz / nbx) * 128;
  const int n0 = (swz % nbx) * 256;

  // staging lane roles: lane l -> subtile row l>>2, pre-swizzled chunk
  const int rl = lane >> 2;
  const int ch = (lane & 3) ^ (((lane >> 5) & 1) << 1);
  const u16* pA_ = A + (size_t)(m0 + w * 16 + rl) * K + ch * 8;
  const u16* pB_ = B + (size_t)(n0 + w * 16 + rl) * K + ch * 8;

  // fragment-read offset within a subtile (u16 units), read-side swizzle
  const int fro = lane16 * 32 + ((quad * 8) ^ ((lane16 & 8) << 1));

  f32x4 zero4 = {0.f, 0.f, 0.f, 0.f};
  f32x4 acc[4][4];
#pragma unroll
  for (int i = 0; i < 4; ++i)
#pragma unroll
    for (int j = 0; j < 4; ++j) acc[i][j] = zero4;

  // software-pipelined operand registers
  bf16x8 a0[2][2], a1[2][2];  // M-half 0 / 1: 2 frags x 2 ks
  bf16x8 Bf[4][2];            // full N: 4 frags x 2 ks

#define STAGE_A(BUF, KO)                                         \
  do {                                                           \
    const u16* _s = pA_ + (KO);                                  \
    u16* _d = &sA[BUF][w * 1024];                                \
    gl_lds16(_s, _d);                                            \
    gl_lds16(_s + 32, _d + 512);                                 \
  } while (0)
#define STAGE_B(BUF, H, KO)                                      \
  do {                                                           \
    const u16* _s = pB_ + (size_t)(H) * 128 * K + (KO);          \
    u16* _d = &sB[BUF][(H) * 8192 + w * 1024];                   \
    gl_lds16(_s, _d);                                            \
    gl_lds16(_s + 32, _d + 512);                                 \
  } while (0)
#define READ_A(DST, BUF, MH)                                                         \
  _Pragma("unroll") for (int i = 0; i < 2; ++i)                                      \
  _Pragma("unroll") for (int ks = 0; ks < 2; ++ks)                                   \
    DST[i][ks] = *(const bf16x8*)&sA[BUF][((wm * 4 + (MH) * 2 + i) * 2 + ks) * 512 + fro];
#define READ_BF(BUF)                                                                 \
  _Pragma("unroll") for (int j = 0; j < 4; ++j)                                      \
  _Pragma("unroll") for (int ks = 0; ks < 2; ++ks)                                   \
    Bf[j][ks] = *(const bf16x8*)&sB[BUF][((wn * 4 + j) * 2 + ks) * 512 + fro];
#define MFMA_H(AF, MH)                                                               \
  __builtin_amdgcn_s_setprio(1);                                                     \
  _Pragma("unroll") for (int i = 0; i < 2; ++i)                                      \
  _Pragma("unroll") for (int j = 0; j < 4; ++j)                                      \
  _Pragma("unroll") for (int ks = 0; ks < 2; ++ks)                                   \
    acc[(MH) * 2 + i][j] = __builtin_amdgcn_mfma_f32_16x16x32_bf16(                  \
        AF[i][ks], Bf[j][ks], acc[(MH) * 2 + i][j], 0, 0, 0);                        \
  __builtin_amdgcn_s_setprio(0);
#define GBAR() __builtin_amdgcn_s_barrier()
#define VMCNT4() asm volatile("s_waitcnt vmcnt(4)" ::: "memory")
#define VMCNT6() asm volatile("s_waitcnt vmcnt(6)" ::: "memory")

  // prologue: tile0 -> buf0 (B 4 + A 2), tile1 -> buf1 (6); vmcnt(6) drains
  // tile0 (tile1's 6 stay in flight); pre-read P1's operands.
  STAGE_B(0, 0, 0); STAGE_B(0, 1, 0); STAGE_A(0, 0);
  STAGE_B(1, 0, 64); STAGE_B(1, 1, 64); STAGE_A(1, 64);
  VMCNT6();
  GBAR();
  READ_A(a0, 0, 0); READ_BF(0);

  const int nIt = K >> 7;
  for (int it = 0; it < nIt; ++it) {
    int base = it << 7;
    int k2 = base + 128; if (k2 >= K) k2 = 0;  // tile 2it+2 (wrapped: never read)
    int k3 = base + 192; if (k3 >= K) k3 = 0;  // tile 2it+3 (wrapped: never read)
    // P1: MFMA(M0, t)
    GBAR();
    MFMA_H(a0, 0);
    STAGE_B(0, 0, k2); STAGE_B(0, 1, k2);
    READ_A(a1, 0, 1);
    // P2: MFMA(M1, t); t+1 must be landed for body reads
    VMCNT4();
    GBAR();
    MFMA_H(a1, 1);
    STAGE_A(0, k2);
    READ_BF(1); READ_A(a0, 1, 0);
    // P3: MFMA(M0, t+1)
    GBAR();
    MFMA_H(a0, 0);
    STAGE_B(1, 0, k3); STAGE_B(1, 1, k3);
    READ_A(a1, 1, 1);
    // P4: MFMA(M1, t+1); t+2 must be landed for body reads
    VMCNT4();
    GBAR();
    MFMA_H(a1, 1);
    STAGE_A(1, k3);
    READ_BF(0); READ_A(a0, 0, 0);
  }
  asm volatile("s_waitcnt vmcnt(0)" ::: "memory");  // drain tail prefetches

#pragma unroll
  for (int i = 0; i < 4; ++i)
#pragma unroll
    for (int j = 0; j < 4; ++j)
#pragma unroll
      for (int r = 0; r < 4; ++r) {
        int row = m0 + wm * 64 + i * 16 + quad * 4 + r;
        int col = n0 + wn * 64 + j * 16 + lane16;
        if (F32OUT)
          ((float*)Cv)[(size_t)row * N + col] = acc[i][j][r];
        else
          ((u16*)Cv)[(size_t)row * N + col] = f2b(acc[i][j][r]);
      }
#undef STAGE_A
#undef STAGE_B
#undef READ_A
#undef READ_BF
#undef MFMA_H
#undef GBAR
#undef VMCNT4
#undef VMCNT6
}

// ---------------- reorg: qkv[B,S,6144] -> q,k [bh,S,D] (roped), vT [bh,D,S] ----------------
__global__ __launch_bounds__(256) void reorg_k(const u16* __restrict__ qkv, const float* __restrict__ tab,
                                               u16* __restrict__ q, u16* __restrict__ k,
                                               u16* __restrict__ vT) {
  __shared__ float vt[64][129];
  int tid = threadIdx.x;
  int st = blockIdx.x, bh = blockIdx.y;
  int b = bh >> 4, h = bh & 15;
  int s0 = st * 64;
  const u16* base = qkv + (size_t)(b * S_LEN + s0) * QKV_N + h * HD;
  u16* qo = q + ((size_t)bh * S_LEN + s0) * HD;
  u16* ko = k + ((size_t)bh * S_LEN + s0) * HD;
#pragma unroll
  for (int p = 0; p < 16; ++p) {
    int e = p * 256 + tid;
    int sl = e >> 6, d = e & 63;
    float c = tab[(s0 + sl) * 128 + d];
    float sn = tab[(s0 + sl) * 128 + 64 + d];
    const u16* rowp = base + (size_t)sl * QKV_N;
    float q1 = b2f(rowp[d]), q2 = b2f(rowp[d + 64]);
    qo[sl * HD + d] = f2b(q1 * c - q2 * sn);
    qo[sl * HD + d + 64] = f2b(q2 * c + q1 * sn);
    float k1 = b2f(rowp[2048 + d]), k2 = b2f(rowp[2048 + d + 64]);
    ko[sl * HD + d] = f2b(k1 * c - k2 * sn);
    ko[sl * HD + d + 64] = f2b(k2 * c + k1 * sn);
  }
#pragma unroll
  for (int p = 0; p < 32; ++p) {
    int e = p * 256 + tid;
    int sl = e >> 7, d = e & 127;
    vt[sl][d] = b2f(base[(size_t)sl * QKV_N + 4096 + d]);
  }
  __syncthreads();
  u16* vo = vT + (size_t)bh * HD * S_LEN;
#pragma unroll
  for (int p = 0; p < 32; ++p) {
    int e = p * 256 + tid;
    int d = e >> 6, sl = e & 63;
    vo[(size_t)d * S_LEN + s0 + sl] = f2b(vt[sl][d]);
  }
}

// ---------------- flash attention, diagonal-paired q-tiles ----------------
__global__ __launch_bounds__(256) void attn_k(const u16* __restrict__ q, const u16* __restrict__ k,
                                              const u16* __restrict__ vT, const float* __restrict__ bias,
                                              u16* __restrict__ ctx) {
  __shared__ __align__(16) u16 Ks[64 * 128];
  __shared__ __align__(16) u16 VTs[128 * 64];
  __shared__ __align__(16) u16 QP[64 * 128];
  __shared__ float bias_s[128];
  int tid = threadIdx.x;
  int lane = tid & 63, wq = tid >> 6;
  int lane16 = lane & 15, quad = lane >> 4;
  int r7 = lane16 & 7;
  int bh = blockIdx.y;
  int b = bh >> 4, h = bh & 15;
  const u16* kg = k + (size_t)bh * S_LEN * HD;
  const u16* vg = vT + (size_t)bh * HD * S_LEN;
  const float* biasr = bias + h * 2048;
  const float scale = 0.08838834764831845f;
  f32x4 zero4 = {0.f, 0.f, 0.f, 0.f};

  int rl4 = lane >> 4, pk = lane & 15;
  int rl8 = lane >> 3, pv = lane & 7;
  u16* Pw = QP + wq * 1152;

  for (int half = 0; half < 2; ++half) {
    int qt = half ? (31 - blockIdx.x) : blockIdx.x;
    int q0 = qt * 64;
    const u16* qg = q + ((size_t)bh * S_LEN + q0) * HD;

    __syncthreads();
    {
      int r = tid >> 4, c = (tid & 15) * 8;
#pragma unroll
      for (int p = 0; p < 4; ++p)
        *(u16x8*)&QP[(r + p * 16) * 128 + c] = *(const u16x8*)&qg[(size_t)(r + p * 16) * HD + c];
    }
    __syncthreads();
    bf16x8 qf[4];
#pragma unroll
    for (int kd = 0; kd < 4; ++kd)
      qf[kd] = *(const bf16x8*)&QP[(wq * 16 + lane16) * 128 + kd * 32 + quad * 8];
    __syncthreads();

    float m_i[4], l_i[4];
    f32x4 o[8];
#pragma unroll
    for (int r = 0; r < 4; ++r) { m_i[r] = -1e30f; l_i[r] = 0.f; }
#pragma unroll
    for (int dt = 0; dt < 8; ++dt) o[dt] = zero4;

    for (int kt = 0; kt <= qt; ++kt) {
      int k0 = kt * 64;
      if (kt) __syncthreads();
#pragma unroll
      for (int t = 0; t < 4; ++t) {
        int g = wq * 4 + t;
        int rowk = g * 4 + rl4;
        int ck = (pk & 8) | ((pk & 7) ^ (rowk & 7));
        gl_lds16(kg + (size_t)(k0 + rowk) * HD + ck * 8, Ks + g * 512);
        int rowv = g * 8 + rl8;
        int cv = pv ^ (rowv & 7);
        gl_lds16(vg + (size_t)rowv * S_LEN + k0 + cv * 8, VTs + g * 512);
      }
      if (tid < 128) {
        int dist = q0 - k0 + tid - 64;
        bias_s[tid] = (dist >= 0) ? biasr[dist] : 0.f;
      }
      __syncthreads();

      f32x4 sc[4];
#pragma unroll
      for (int j = 0; j < 4; ++j) sc[j] = zero4;
#pragma unroll
      for (int kd = 0; kd < 4; ++kd)
#pragma unroll
        for (int j = 0; j < 4; ++j) {
          int cd = kd * 4 + quad;
          int pos = (cd & 8) | ((cd & 7) ^ r7);
          bf16x8 kf = *(const bf16x8*)&Ks[(j * 16 + lane16) * 128 + pos * 8];
          sc[j] = __builtin_amdgcn_mfma_f32_16x16x32_bf16(qf[kd], kf, sc[j], 0, 0, 0);
        }

      int qrel = wq * 16 + quad * 4;
#pragma unroll
      for (int j = 0; j < 4; ++j) {
        int krel = j * 16 + lane16;
#pragma unroll
        for (int r = 0; r < 4; ++r) {
          bool valid = (q0 + qrel + r) >= (k0 + krel);
          float sv = sc[j][r] * scale + bias_s[64 + (qrel + r) - krel];
          sc[j][r] = valid ? sv : -1e30f;
        }
      }
      float mx[4];
#pragma unroll
      for (int r = 0; r < 4; ++r)
        mx[r] = fmaxf(fmaxf(sc[0][r], sc[1][r]), fmaxf(sc[2][r], sc[3][r]));
#pragma unroll
      for (int xm = 1; xm < 16; xm <<= 1)
#pragma unroll
        for (int r = 0; r < 4; ++r) mx[r] = fmaxf(mx[r], __shfl_xor(mx[r], xm));
      float alpha[4];
#pragma unroll
      for (int r = 0; r < 4; ++r) {
        float mn = fmaxf(m_i[r], mx[r]);
        alpha[r] = __expf(m_i[r] - mn);
        m_i[r] = mn;
      }
#pragma unroll
      for (int j = 0; j < 4; ++j)
#pragma unroll
        for (int r = 0; r < 4; ++r) sc[j][r] = __expf(sc[j][r] - m_i[r]);
      float rs[4];
#pragma unroll
      for (int r = 0; r < 4; ++r) rs[r] = (sc[0][r] + sc[1][r]) + (sc[2][r] + sc[3][r]);
#pragma unroll
      for (int xm = 1; xm < 16; xm <<= 1)
#pragma unroll
        for (int r = 0; r < 4; ++r) rs[r] += __shfl_xor(rs[r], xm);
#pragma unroll
      for (int r = 0; r < 4; ++r) l_i[r] = l_i[r] * alpha[r] + rs[r];
#pragma unroll
      for (int dt = 0; dt < 8; ++dt)
#pragma unroll
        for (int r = 0; r < 4; ++r) o[dt][r] *= alpha[r];

#pragma unroll
      for (int j = 0; j < 4; ++j)
#pragma unroll
        for (int r = 0; r < 4; ++r)
          Pw[(quad * 4 + r) * 72 + j * 16 + lane16] = f2b(sc[j][r]);
      __threadfence_block();

#pragma unroll
      for (int ks = 0; ks < 2; ++ks) {
        bf16x8 pf = *(const bf16x8*)&Pw[lane16 * 72 + ks * 32 + quad * 8];
#pragma unroll
        for (int dt = 0; dt < 8; ++dt) {
          int cdv = ks * 4 + quad;
          int posv = cdv ^ r7;
          bf16x8 vf = *(const bf16x8*)&VTs[(dt * 16 + lane16) * 64 + posv * 8];
          o[dt] = __builtin_amdgcn_mfma_f32_16x16x32_bf16(pf, vf, o[dt], 0, 0, 0);
        }
      }
    }
#pragma unroll
    for (int r = 0; r < 4; ++r) {
      float invl = 1.0f / l_i[r];
      int srow = q0 + wq * 16 + quad * 4 + r;
      u16* orow = ctx + ((size_t)b * S_LEN + srow) * HID + h * HD;
#pragma unroll
      for (int dt = 0; dt < 8; ++dt)
        orow[dt * 16 + lane16] = f2b(o[dt][r] * invl);
    }
  }
}

extern "C" void kernel_launch(void* const* d_in, const int* in_sizes, int n_in,
                              void* d_out, int out_size, void* d_ws, size_t ws_size,
                              hipStream_t stream) {
  const void* x       = d_in[0];
  const void* qkv_w   = d_in[1];
  const void* dense_w = d_in[2];
  const void* rtable  = d_in[3];
  char* ws = (char*)d_ws;

  int*   flag  = (int*)(ws);
  float* bias  = (float*)(ws + 256);
  float* tab   = (float*)(ws + 131328);
  u16*   wdT   = (u16*)(ws + 1179904);
  u16*   vT    = (u16*)(ws + 9568512);
  u16*   x_bf  = (u16*)(ws + 26345728);
  u16*   qA    = x_bf;
  u16*   wqkvT = (u16*)(ws + 43122944);
  u16*   kA    = wqkvT;
  u16*   qkv   = (u16*)(ws + 68288768);
  u16*   ctx   = qkv;

  detect_dtype_k<<<1, 256, 0, stream>>>(x, flag);
  convert_any_k<<<8192, 256, 0, stream>>>(x, x_bf, flag);
  transpose_any<<<dim3(96, 32), 256, 0, stream>>>(qkv_w, wqkvT, 2048, 6144, flag);
  transpose_any<<<dim3(32, 32), 256, 0, stream>>>(dense_w, wdT, 2048, 2048, flag);
  rope_table_k<<<512, 256, 0, stream>>>(tab);
  build_bias_k<<<128, 256, 0, stream>>>(rtable, bias, flag);
  // QKV: 32x24 = 768 blocks = 3 exact rounds on 256 CUs
  gemm128_bt<false><<<dim3(24, 32), 512, 0, stream>>>(x_bf, wqkvT, qkv, 4096, 6144, 2048);
  reorg_k<<<dim3(32, 32), 256, 0, stream>>>(qkv, tab, qA, kA, vT);
  attn_k<<<dim3(16, 32), 256, 0, stream>>>(qA, kA, vT, bias, ctx);
  // out-proj: 32x8 = 256 blocks = 1 exact round
  gemm128_bt<true><<<dim3(8, 32), 512, 0, stream>>>(ctx, wdT, d_out, 4096, 2048, 2048);
}

// Round 8
// 433.659 us; speedup vs baseline: 1.0767x; 1.0767x over previous
//
#include <hip/hip_runtime.h>

typedef unsigned short u16;
typedef __bf16 bf16_t;
typedef __bf16 bf16x8 __attribute__((ext_vector_type(8)));
typedef float f32x4 __attribute__((ext_vector_type(4)));
typedef unsigned short u16x8 __attribute__((ext_vector_type(8)));
typedef unsigned short u16x4 __attribute__((ext_vector_type(4)));

#define S_LEN 2048
#define NHEAD 16
#define HD 128
#define HID 2048
#define QKV_N 6144

__device__ __forceinline__ float b2f(u16 u) {
  union { unsigned int i; float f; } x; x.i = ((unsigned int)u) << 16; return x.f;
}
__device__ __forceinline__ u16 f2b(float f) {
  bf16_t h = (bf16_t)f;
  return __builtin_bit_cast(unsigned short, h);
}

// async global->LDS, 16B per lane. lds dest must be wave-uniform; data lands at
// dest + lane*16.
__device__ __forceinline__ void gl_lds16(const u16* g, u16* l) {
  __builtin_amdgcn_global_load_lds(
      (const __attribute__((address_space(1))) unsigned int*)g,
      (__attribute__((address_space(3))) unsigned int*)l, 16, 0, 0);
}

// ---------------- dtype sniffer: 1 if fp32, 0 if bf16 ----------------
__global__ void detect_dtype_k(const void* __restrict__ x, int* __restrict__ flag) {
  __shared__ int cnt;
  if (threadIdx.x == 0) cnt = 0;
  __syncthreads();
  const u16* xu = (const u16*)x;
  int sane = 0;
  for (int i = threadIdx.x; i < 8192; i += 256) {
    int e = (xu[i] >> 7) & 0xFF;
    if (e == 0 || (e > 100 && e < 140)) sane++;
  }
  atomicAdd(&cnt, sane);
  __syncthreads();
  if (threadIdx.x == 0) *flag = (cnt < 7373) ? 1 : 0;
}

// ---------------- convert input (fp32|bf16) -> bf16 ----------------
__global__ __launch_bounds__(256) void convert_any_k(const void* __restrict__ in, u16* __restrict__ out,
                                                     const int* __restrict__ flag) {
  int i = (blockIdx.x * 256 + threadIdx.x) * 4;
  if (*flag) {
    const float4 v = *(const float4*)((const float*)in + i);
    u16x4 o = {f2b(v.x), f2b(v.y), f2b(v.z), f2b(v.w)};
    *(u16x4*)(out + i) = o;
  } else {
    *(u16x4*)(out + i) = *(const u16x4*)((const u16*)in + i);
  }
}

// ---------------- transpose [R][C] -> [C][R], (fp32|bf16) in -> bf16 out ----------------
__global__ __launch_bounds__(256) void transpose_any(const void* __restrict__ in,
                                                     u16* __restrict__ out, int R, int C,
                                                     const int* __restrict__ flag) {
  __shared__ u16 t[64][65];
  bool isf = (*flag != 0);
  int tid = threadIdx.x;
  int r0 = blockIdx.y * 64, c0 = blockIdx.x * 64;
#pragma unroll
  for (int p = 0; p < 16; ++p) {
    int e = p * 256 + tid;
    int r = e >> 6, c = e & 63;
    size_t idx = (size_t)(r0 + r) * C + (c0 + c);
    t[r][c] = isf ? f2b(((const float*)in)[idx]) : ((const u16*)in)[idx];
  }
  __syncthreads();
#pragma unroll
  for (int p = 0; p < 16; ++p) {
    int e = p * 256 + tid;
    int r = e >> 6, c = e & 63;
    out[(size_t)(c0 + r) * R + (r0 + c)] = t[c][r];
  }
}

// ---------------- RoPE cos/sin table ----------------
__global__ void rope_table_k(float* __restrict__ tab) {
  int i = blockIdx.x * 256 + threadIdx.x;
  int s = i >> 6, d = i & 63;
  float inv = expf(-(float)d * (9.210340371976184f / 64.0f));
  float ang = (float)s * inv;
  tab[s * 128 + d] = cosf(ang);
  tab[s * 128 + 64 + d] = sinf(ang);
}

// ---------------- relative bias ----------------
__global__ void build_bias_k(const void* __restrict__ table, float* __restrict__ bias,
                             const int* __restrict__ flag) {
  int i = blockIdx.x * 256 + threadIdx.x;
  int h = i >> 11, dist = i & 2047;
  int bucket;
  if (dist < 16) bucket = dist;
  else {
    int lb = (int)(logf((float)dist * 0.0625f) / 2.0794415f * 16.0f) + 16;
    bucket = lb < 31 ? lb : 31;
  }
  int ti = bucket * NHEAD + h;
  float tv = (*flag) ? ((const float*)table)[ti] : b2f(((const u16*)table)[ti]);
  bias[h * 2048 + dist] = tv;
}

// ---------------- GEMM 256x256, 8-phase, reg-pipelined, 1 barrier/phase ----------------
// C = A[M][K] * B[N][K]^T. Requires M%256==0, N%256==0, K%128==0, nwg%8==0.
// 8 waves (2M x 4N), BK=64, LDS 128 KiB, st_16x32 XOR swizzle (both-sides:
// inverse-swizzled global source + swizzled ds_read offset).
//
// r8: REVERTED to the r4 schedule -- best measured for this shape (113.0 us,
// MfmaUtil 38.1, per-block util ~51%). r5/r6's SGB interleave regressed (-10%);
// r7's 128x256 tile regressed (-27%: staging/compute ratio 1.5x worse + B-panel
// L2 reuse collapse, FETCH 181->311MB). Schedule variants r1-r6 bracketed this
// structure at 44-51% per-block util => HIP-level scheduling saturated; the
// remaining gap is the 384-block/256-CU 1.5-round tail (no clean tiling escape:
// BN=384 register-infeasible, split-K reduction costs more than the tail).
//
// Register pipeline: phase p's ds_reads load operands for p+1; MFMA_p consumes
// registers read at p-1 (>=1 phase in flight -> lgkm stall ~0). Phase =
// [stage; (vmcnt at P4/P8); BAR; MFMA_p; READS_{p+1}]. MFMA precedes reads in
// program order so reg WARs (b0 overwrite at P4/P8) are pinned by deps.
// Quadrant order per tile: P1 (M0,N0) P2 (M0,N1) P3 (M1,N1) P4 (M1,N0).
// Visibility: vmcnt(8)@P4 drains t+1 (issued P7'/P8') before BAR -> P4-P6
// reads of buf1 safe; vmcnt(8)@P8 drains t+2 (issued P3/P4) -> P8-P2 reads of
// buf0 safe. WAR stage-vs-read has a FULL barrier in every case:
// P1-rd/BAR2/P3-st, P2-rd/BAR3/P4-st, P4+P5-rd/BAR6/P7-st, P6-rd/BAR7/P8-st.
// Tail: last P8's reads target tile 2*nIt (never consumed; dead regs).
template <bool F32OUT>
__global__ __launch_bounds__(512, 2) void gemm256_bt(const u16* __restrict__ A,
                                                     const u16* __restrict__ B,
                                                     void* __restrict__ Cv,
                                                     int M, int N, int K) {
  __shared__ __align__(16) u16 sA[2][16384];
  __shared__ __align__(16) u16 sB[2][16384];
  (void)M;
  const int tid = threadIdx.x;
  const int lane = tid & 63, w = tid >> 6;
  const int wm = w >> 2, wn = w & 3;
  const int lane16 = lane & 15, quad = lane >> 4;

  // T1: XCD-aware bijective block swizzle (nwg % 8 == 0)
  const int nbx = gridDim.x;
  const int nwg = nbx * gridDim.y;
  const int bid = blockIdx.y * nbx + blockIdx.x;
  const int cpx = nwg >> 3;
  const int swz = (bid & 7) * cpx + (bid >> 3);
  const int m0 = (swz / nbx) * 256;
  const int n0 = (swz % nbx) * 256;

  // staging lane roles: lane l -> subtile row l>>2, pre-swizzled chunk
  const int rl = lane >> 2;
  const int ch = (lane & 3) ^ (((lane >> 5) & 1) << 1);
  const u16* pA_ = A + (size_t)(m0 + w * 16 + rl) * K + ch * 8;
  const u16* pB_ = B + (size_t)(n0 + w * 16 + rl) * K + ch * 8;

  // fragment-read offset within a subtile pair (u16 units), read-side swizzle
  const int fro = lane16 * 32 + ((quad * 8) ^ ((lane16 & 8) << 1));

  f32x4 zero4 = {0.f, 0.f, 0.f, 0.f};
  f32x4 acc[8][4];
#pragma unroll
  for (int i = 0; i < 8; ++i)
#pragma unroll
    for (int j = 0; j < 4; ++j) acc[i][j] = zero4;

  // software-pipelined operand registers (single-buffered)
  bf16x8 a0[4][2], a1[4][2];   // M-half 0 / 1: 4 frags x 2 ks
  bf16x8 b0[2][2], b1[2][2];   // N-half 0 / 1: 2 frags x 2 ks

#define STAGE_A(BUF, H, KO)                                      \
  do {                                                           \
    const u16* _s = pA_ + (size_t)(H) * 128 * K + (KO);          \
    u16* _d = &sA[BUF][(H) * 8192 + w * 1024];                   \
    gl_lds16(_s, _d);                                            \
    gl_lds16(_s + 32, _d + 512);                                 \
  } while (0)
#define STAGE_B(BUF, H, KO)                                      \
  do {                                                           \
    const u16* _s = pB_ + (size_t)(H) * 128 * K + (KO);          \
    u16* _d = &sB[BUF][(H) * 8192 + w * 1024];                   \
    gl_lds16(_s, _d);                                            \
    gl_lds16(_s + 32, _d + 512);                                 \
  } while (0)
#define READ_A(DST, BUF, MH)                                                         \
  _Pragma("unroll") for (int i = 0; i < 4; ++i)                                      \
  _Pragma("unroll") for (int ks = 0; ks < 2; ++ks)                                   \
    DST[i][ks] = *(const bf16x8*)&sA[BUF][((wm * 8 + (MH) * 4 + i) * 2 + ks) * 512 + fro];
#define READ_B(DST, BUF, NH)                                                         \
  _Pragma("unroll") for (int j = 0; j < 2; ++j)                                      \
  _Pragma("unroll") for (int ks = 0; ks < 2; ++ks)                                   \
    DST[j][ks] = *(const bf16x8*)&sB[BUF][((wn * 4 + (NH) * 2 + j) * 2 + ks) * 512 + fro];
#define MFMA_Q(AF, BF, MH, NH)                                                       \
  __builtin_amdgcn_s_setprio(1);                                                     \
  _Pragma("unroll") for (int i = 0; i < 4; ++i)                                      \
  _Pragma("unroll") for (int j = 0; j < 2; ++j)                                      \
  _Pragma("unroll") for (int ks = 0; ks < 2; ++ks)                                   \
    acc[(MH) * 4 + i][(NH) * 2 + j] = __builtin_amdgcn_mfma_f32_16x16x32_bf16(       \
        AF[i][ks], BF[j][ks], acc[(MH) * 4 + i][(NH) * 2 + j], 0, 0, 0);             \
  __builtin_amdgcn_s_setprio(0);
#define GBAR() __builtin_amdgcn_s_barrier()
#define VMCNT8() asm volatile("s_waitcnt vmcnt(8)" ::: "memory")

  // prologue: tile0 fully -> buf0, tile1 fully -> buf1 (16 loads);
  // vmcnt(8) drains tile0 (tile1's 8 stay in flight); pre-read P1's operands.
  STAGE_A(0, 0, 0); STAGE_A(0, 1, 0);
  STAGE_B(0, 0, 0); STAGE_B(0, 1, 0);
  STAGE_B(1, 0, 64); STAGE_B(1, 1, 64);
  STAGE_A(1, 0, 64); STAGE_A(1, 1, 64);
  VMCNT8();
  GBAR();
  READ_A(a0, 0, 0); READ_B(b0, 0, 0);

  const int nIt = K >> 7;
  for (int it = 0; it < nIt; ++it) {
    int base = it << 7;
    int k2 = base + 128; if (k2 >= K) k2 = 0;  // tile 2it+2 (wrapped: never read)
    int k3 = base + 192; if (k3 >= K) k3 = 0;  // tile 2it+3 (wrapped: never read)
    // P1
    GBAR(); MFMA_Q(a0, b0, 0, 0);
    READ_B(b1, 0, 1);
    // P2
    GBAR(); MFMA_Q(a0, b1, 0, 1);
    READ_A(a1, 0, 1);
    // P3
    STAGE_B(0, 0, k2); STAGE_B(0, 1, k2);
    GBAR(); MFMA_Q(a1, b1, 1, 1);
    // P4
    STAGE_A(0, 0, k2); STAGE_A(0, 1, k2);
    VMCNT8();
    GBAR(); MFMA_Q(a1, b0, 1, 0);
    READ_A(a0, 1, 0); READ_B(b0, 1, 0);
    // P5
    GBAR(); MFMA_Q(a0, b0, 0, 0);
    READ_B(b1, 1, 1);
    // P6
    GBAR(); MFMA_Q(a0, b1, 0, 1);
    READ_A(a1, 1, 1);
    // P7
    STAGE_B(1, 0, k3); STAGE_B(1, 1, k3);
    GBAR(); MFMA_Q(a1, b1, 1, 1);
    // P8
    STAGE_A(1, 0, k3); STAGE_A(1, 1, k3);
    VMCNT8();
    GBAR(); MFMA_Q(a1, b0, 1, 0);
    READ_A(a0, 0, 0); READ_B(b0, 0, 0);
  }
  asm volatile("s_waitcnt vmcnt(0)" ::: "memory");  // drain tail prefetches

#pragma unroll
  for (int i = 0; i < 8; ++i)
#pragma unroll
    for (int j = 0; j < 4; ++j)
#pragma unroll
      for (int r = 0; r < 4; ++r) {
        int row = m0 + wm * 128 + i * 16 + quad * 4 + r;
        int col = n0 + wn * 64 + j * 16 + lane16;
        if (F32OUT)
          ((float*)Cv)[(size_t)row * N + col] = acc[i][j][r];
        else
          ((u16*)Cv)[(size_t)row * N + col] = f2b(acc[i][j][r]);
      }
#undef STAGE_A
#undef STAGE_B
#undef READ_A
#undef READ_B
#undef MFMA_Q
#undef GBAR
#undef VMCNT8
}

// ---------------- GEMM 128x256, 4-phase, reg-pipelined (out-projection only) ---------
// Kept ONLY for the output projection (N=2048): grid 8x32 = 256 blocks = 1
// exact round, B-panel sharing tight. (As the QKV GEMM this tile regressed:
// r7 measured 143.7us / MfmaUtil 28.7 / FETCH +72% -- staging/compute ratio
// 1.5x worse and B-panel L2 reuse collapse at N=6144. r7-vs-r6 remainder
// arithmetic shows it beats the m97 2-round kernel on the out-proj shape.)
// Schedule/hazard/vmcnt ledger identical to r7 header comment.
template <bool F32OUT>
__global__ __launch_bounds__(512, 2) void gemm128_bt(const u16* __restrict__ A,
                                                     const u16* __restrict__ B,
                                                     void* __restrict__ Cv,
                                                     int M, int N, int K) {
  __shared__ __align__(16) u16 sA[2][8192];    // 128 x 64, 16 subtiles/buf
  __shared__ __align__(16) u16 sB[2][16384];   // 256 x 64, 32 subtiles/buf
  (void)M;
  const int tid = threadIdx.x;
  const int lane = tid & 63, w = tid >> 6;
  const int wm = w >> 2, wn = w & 3;
  const int lane16 = lane & 15, quad = lane >> 4;

  const int nbx = gridDim.x;
  const int nwg = nbx * gridDim.y;
  const int bid = blockIdx.y * nbx + blockIdx.x;
  const int cpx = nwg >> 3;
  const int swz = (bid & 7) * cpx + (bid >> 3);
  const int m0 = (swz / nbx) * 128;
  const int n0 = (swz % nbx) * 256;

  const int rl = lane >> 2;
  const int ch = (lane & 3) ^ (((lane >> 5) & 1) << 1);
  const u16* pA_ = A + (size_t)(m0 + w * 16 + rl) * K + ch * 8;
  const u16* pB_ = B + (size_t)(n0 + w * 16 + rl) * K + ch * 8;

  const int fro = lane16 * 32 + ((quad * 8) ^ ((lane16 & 8) << 1));

  f32x4 zero4 = {0.f, 0.f, 0.f, 0.f};
  f32x4 acc[4][4];
#pragma unroll
  for (int i = 0; i < 4; ++i)
#pragma unroll
    for (int j = 0; j < 4; ++j) acc[i][j] = zero4;

  bf16x8 a0[2][2], a1[2][2];  // M-half 0 / 1: 2 frags x 2 ks
  bf16x8 Bf[4][2];            // full N: 4 frags x 2 ks

#define STAGE_A(BUF, KO)                                         \
  do {                                                           \
    const u16* _s = pA_ + (KO);                                  \
    u16* _d = &sA[BUF][w * 1024];                                \
    gl_lds16(_s, _d);                                            \
    gl_lds16(_s + 32, _d + 512);                                 \
  } while (0)
#define STAGE_B(BUF, H, KO)                                      \
  do {                                                           \
    const u16* _s = pB_ + (size_t)(H) * 128 * K + (KO);          \
    u16* _d = &sB[BUF][(H) * 8192 + w * 1024];                   \
    gl_lds16(_s, _d);                                            \
    gl_lds16(_s + 32, _d + 512);                                 \
  } while (0)
#define READ_A(DST, BUF, MH)                                                         \
  _Pragma("unroll") for (int i = 0; i < 2; ++i)                                      \
  _Pragma("unroll") for (int ks = 0; ks < 2; ++ks)                                   \
    DST[i][ks] = *(const bf16x8*)&sA[BUF][((wm * 4 + (MH) * 2 + i) * 2 + ks) * 512 + fro];
#define READ_BF(BUF)                                                                 \
  _Pragma("unroll") for (int j = 0; j < 4; ++j)                                      \
  _Pragma("unroll") for (int ks = 0; ks < 2; ++ks)                                   \
    Bf[j][ks] = *(const bf16x8*)&sB[BUF][((wn * 4 + j) * 2 + ks) * 512 + fro];
#define MFMA_H(AF, MH)                                                               \
  __builtin_amdgcn_s_setprio(1);                                                     \
  _Pragma("unroll") for (int i = 0; i < 2; ++i)                                      \
  _Pragma("unroll") for (int j = 0; j < 4; ++j)                                      \
  _Pragma("unroll") for (int ks = 0; ks < 2; ++ks)                                   \
    acc[(MH) * 2 + i][j] = __builtin_amdgcn_mfma_f32_16x16x32_bf16(                  \
        AF[i][ks], Bf[j][ks], acc[(MH) * 2 + i][j], 0, 0, 0);                        \
  __builtin_amdgcn_s_setprio(0);
#define GBAR() __builtin_amdgcn_s_barrier()
#define VMCNT4() asm volatile("s_waitcnt vmcnt(4)" ::: "memory")
#define VMCNT6() asm volatile("s_waitcnt vmcnt(6)" ::: "memory")

  STAGE_B(0, 0, 0); STAGE_B(0, 1, 0); STAGE_A(0, 0);
  STAGE_B(1, 0, 64); STAGE_B(1, 1, 64); STAGE_A(1, 64);
  VMCNT6();
  GBAR();
  READ_A(a0, 0, 0); READ_BF(0);

  const int nIt = K >> 7;
  for (int it = 0; it < nIt; ++it) {
    int base = it << 7;
    int k2 = base + 128; if (k2 >= K) k2 = 0;
    int k3 = base + 192; if (k3 >= K) k3 = 0;
    // P1: MFMA(M0, t)
    GBAR();
    MFMA_H(a0, 0);
    STAGE_B(0, 0, k2); STAGE_B(0, 1, k2);
    READ_A(a1, 0, 1);
    // P2: MFMA(M1, t); t+1 must be landed for body reads
    VMCNT4();
    GBAR();
    MFMA_H(a1, 1);
    STAGE_A(0, k2);
    READ_BF(1); READ_A(a0, 1, 0);
    // P3: MFMA(M0, t+1)
    GBAR();
    MFMA_H(a0, 0);
    STAGE_B(1, 0, k3); STAGE_B(1, 1, k3);
    READ_A(a1, 1, 1);
    // P4: MFMA(M1, t+1); t+2 must be landed for body reads
    VMCNT4();
    GBAR();
    MFMA_H(a1, 1);
    STAGE_A(1, k3);
    READ_BF(0); READ_A(a0, 0, 0);
  }
  asm volatile("s_waitcnt vmcnt(0)" ::: "memory");

#pragma unroll
  for (int i = 0; i < 4; ++i)
#pragma unroll
    for (int j = 0; j < 4; ++j)
#pragma unroll
      for (int r = 0; r < 4; ++r) {
        int row = m0 + wm * 64 + i * 16 + quad * 4 + r;
        int col = n0 + wn * 64 + j * 16 + lane16;
        if (F32OUT)
          ((float*)Cv)[(size_t)row * N + col] = acc[i][j][r];
        else
          ((u16*)Cv)[(size_t)row * N + col] = f2b(acc[i][j][r]);
      }
#undef STAGE_A
#undef STAGE_B
#undef READ_A
#undef READ_BF
#undef MFMA_H
#undef GBAR
#undef VMCNT4
#undef VMCNT6
}

// ---------------- reorg: qkv[B,S,6144] -> q,k [bh,S,D] (roped), vT [bh,D,S] ----------------
__global__ __launch_bounds__(256) void reorg_k(const u16* __restrict__ qkv, const float* __restrict__ tab,
                                               u16* __restrict__ q, u16* __restrict__ k,
                                               u16* __restrict__ vT) {
  __shared__ float vt[64][129];
  int tid = threadIdx.x;
  int st = blockIdx.x, bh = blockIdx.y;
  int b = bh >> 4, h = bh & 15;
  int s0 = st * 64;
  const u16* base = qkv + (size_t)(b * S_LEN + s0) * QKV_N + h * HD;
  u16* qo = q + ((size_t)bh * S_LEN + s0) * HD;
  u16* ko = k + ((size_t)bh * S_LEN + s0) * HD;
#pragma unroll
  for (int p = 0; p < 16; ++p) {
    int e = p * 256 + tid;
    int sl = e >> 6, d = e & 63;
    float c = tab[(s0 + sl) * 128 + d];
    float sn = tab[(s0 + sl) * 128 + 64 + d];
    const u16* rowp = base + (size_t)sl * QKV_N;
    float q1 = b2f(rowp[d]), q2 = b2f(rowp[d + 64]);
    qo[sl * HD + d] = f2b(q1 * c - q2 * sn);
    qo[sl * HD + d + 64] = f2b(q2 * c + q1 * sn);
    float k1 = b2f(rowp[2048 + d]), k2 = b2f(rowp[2048 + d + 64]);
    ko[sl * HD + d] = f2b(k1 * c - k2 * sn);
    ko[sl * HD + d + 64] = f2b(k2 * c + k1 * sn);
  }
#pragma unroll
  for (int p = 0; p < 32; ++p) {
    int e = p * 256 + tid;
    int sl = e >> 7, d = e & 127;
    vt[sl][d] = b2f(base[(size_t)sl * QKV_N + 4096 + d]);
  }
  __syncthreads();
  u16* vo = vT + (size_t)bh * HD * S_LEN;
#pragma unroll
  for (int p = 0; p < 32; ++p) {
    int e = p * 256 + tid;
    int d = e >> 6, sl = e & 63;
    vo[(size_t)d * S_LEN + s0 + sl] = f2b(vt[sl][d]);
  }
}

// ---------------- flash attention, diagonal-paired q-tiles ----------------
__global__ __launch_bounds__(256) void attn_k(const u16* __restrict__ q, const u16* __restrict__ k,
                                              const u16* __restrict__ vT, const float* __restrict__ bias,
                                              u16* __restrict__ ctx) {
  __shared__ __align__(16) u16 Ks[64 * 128];
  __shared__ __align__(16) u16 VTs[128 * 64];
  __shared__ __align__(16) u16 QP[64 * 128];
  __shared__ float bias_s[128];
  int tid = threadIdx.x;
  int lane = tid & 63, wq = tid >> 6;
  int lane16 = lane & 15, quad = lane >> 4;
  int r7 = lane16 & 7;
  int bh = blockIdx.y;
  int b = bh >> 4, h = bh & 15;
  const u16* kg = k + (size_t)bh * S_LEN * HD;
  const u16* vg = vT + (size_t)bh * HD * S_LEN;
  const float* biasr = bias + h * 2048;
  const float scale = 0.08838834764831845f;
  f32x4 zero4 = {0.f, 0.f, 0.f, 0.f};

  int rl4 = lane >> 4, pk = lane & 15;
  int rl8 = lane >> 3, pv = lane & 7;
  u16* Pw = QP + wq * 1152;

  for (int half = 0; half < 2; ++half) {
    int qt = half ? (31 - blockIdx.x) : blockIdx.x;
    int q0 = qt * 64;
    const u16* qg = q + ((size_t)bh * S_LEN + q0) * HD;

    __syncthreads();
    {
      int r = tid >> 4, c = (tid & 15) * 8;
#pragma unroll
      for (int p = 0; p < 4; ++p)
        *(u16x8*)&QP[(r + p * 16) * 128 + c] = *(const u16x8*)&qg[(size_t)(r + p * 16) * HD + c];
    }
    __syncthreads();
    bf16x8 qf[4];
#pragma unroll
    for (int kd = 0; kd < 4; ++kd)
      qf[kd] = *(const bf16x8*)&QP[(wq * 16 + lane16) * 128 + kd * 32 + quad * 8];
    __syncthreads();

    float m_i[4], l_i[4];
    f32x4 o[8];
#pragma unroll
    for (int r = 0; r < 4; ++r) { m_i[r] = -1e30f; l_i[r] = 0.f; }
#pragma unroll
    for (int dt = 0; dt < 8; ++dt) o[dt] = zero4;

    for (int kt = 0; kt <= qt; ++kt) {
      int k0 = kt * 64;
      if (kt) __syncthreads();
#pragma unroll
      for (int t = 0; t < 4; ++t) {
        int g = wq * 4 + t;
        int rowk = g * 4 + rl4;
        int ck = (pk & 8) | ((pk & 7) ^ (rowk & 7));
        gl_lds16(kg + (size_t)(k0 + rowk) * HD + ck * 8, Ks + g * 512);
        int rowv = g * 8 + rl8;
        int cv = pv ^ (rowv & 7);
        gl_lds16(vg + (size_t)rowv * S_LEN + k0 + cv * 8, VTs + g * 512);
      }
      if (tid < 128) {
        int dist = q0 - k0 + tid - 64;
        bias_s[tid] = (dist >= 0) ? biasr[dist] : 0.f;
      }
      __syncthreads();

      f32x4 sc[4];
#pragma unroll
      for (int j = 0; j < 4; ++j) sc[j] = zero4;
#pragma unroll
      for (int kd = 0; kd < 4; ++kd)
#pragma unroll
        for (int j = 0; j < 4; ++j) {
          int cd = kd * 4 + quad;
          int pos = (cd & 8) | ((cd & 7) ^ r7);
          bf16x8 kf = *(const bf16x8*)&Ks[(j * 16 + lane16) * 128 + pos * 8];
          sc[j] = __builtin_amdgcn_mfma_f32_16x16x32_bf16(qf[kd], kf, sc[j], 0, 0, 0);
        }

      int qrel = wq * 16 + quad * 4;
#pragma unroll
      for (int j = 0; j < 4; ++j) {
        int krel = j * 16 + lane16;
#pragma unroll
        for (int r = 0; r < 4; ++r) {
          bool valid = (q0 + qrel + r) >= (k0 + krel);
          float sv = sc[j][r] * scale + bias_s[64 + (qrel + r) - krel];
          sc[j][r] = valid ? sv : -1e30f;
        }
      }
      float mx[4];
#pragma unroll
      for (int r = 0; r < 4; ++r)
        mx[r] = fmaxf(fmaxf(sc[0][r], sc[1][r]), fmaxf(sc[2][r], sc[3][r]));
#pragma unroll
      for (int xm = 1; xm < 16; xm <<= 1)
#pragma unroll
        for (int r = 0; r < 4; ++r) mx[r] = fmaxf(mx[r], __shfl_xor(mx[r], xm));
      float alpha[4];
#pragma unroll
      for (int r = 0; r < 4; ++r) {
        float mn = fmaxf(m_i[r], mx[r]);
        alpha[r] = __expf(m_i[r] - mn);
        m_i[r] = mn;
      }
#pragma unroll
      for (int j = 0; j < 4; ++j)
#pragma unroll
        for (int r = 0; r < 4; ++r) sc[j][r] = __expf(sc[j][r] - m_i[r]);
      float rs[4];
#pragma unroll
      for (int r = 0; r < 4; ++r) rs[r] = (sc[0][r] + sc[1][r]) + (sc[2][r] + sc[3][r]);
#pragma unroll
      for (int xm = 1; xm < 16; xm <<= 1)
#pragma unroll
        for (int r = 0; r < 4; ++r) rs[r] += __shfl_xor(rs[r], xm);
#pragma unroll
      for (int r = 0; r < 4; ++r) l_i[r] = l_i[r] * alpha[r] + rs[r];
#pragma unroll
      for (int dt = 0; dt < 8; ++dt)
#pragma unroll
        for (int r = 0; r < 4; ++r) o[dt][r] *= alpha[r];

#pragma unroll
      for (int j = 0; j < 4; ++j)
#pragma unroll
        for (int r = 0; r < 4; ++r)
          Pw[(quad * 4 + r) * 72 + j * 16 + lane16] = f2b(sc[j][r]);
      __threadfence_block();

#pragma unroll
      for (int ks = 0; ks < 2; ++ks) {
        bf16x8 pf = *(const bf16x8*)&Pw[lane16 * 72 + ks * 32 + quad * 8];
#pragma unroll
        for (int dt = 0; dt < 8; ++dt) {
          int cdv = ks * 4 + quad;
          int posv = cdv ^ r7;
          bf16x8 vf = *(const bf16x8*)&VTs[(dt * 16 + lane16) * 64 + posv * 8];
          o[dt] = __builtin_amdgcn_mfma_f32_16x16x32_bf16(pf, vf, o[dt], 0, 0, 0);
        }
      }
    }
#pragma unroll
    for (int r = 0; r < 4; ++r) {
      float invl = 1.0f / l_i[r];
      int srow = q0 + wq * 16 + quad * 4 + r;
      u16* orow = ctx + ((size_t)b * S_LEN + srow) * HID + h * HD;
#pragma unroll
      for (int dt = 0; dt < 8; ++dt)
        orow[dt * 16 + lane16] = f2b(o[dt][r] * invl);
    }
  }
}

extern "C" void kernel_launch(void* const* d_in, const int* in_sizes, int n_in,
                              void* d_out, int out_size, void* d_ws, size_t ws_size,
                              hipStream_t stream) {
  const void* x       = d_in[0];
  const void* qkv_w   = d_in[1];
  const void* dense_w = d_in[2];
  const void* rtable  = d_in[3];
  char* ws = (char*)d_ws;

  int*   flag  = (int*)(ws);
  float* bias  = (float*)(ws + 256);
  float* tab   = (float*)(ws + 131328);
  u16*   wdT   = (u16*)(ws + 1179904);
  u16*   vT    = (u16*)(ws + 9568512);
  u16*   x_bf  = (u16*)(ws + 26345728);
  u16*   qA    = x_bf;
  u16*   wqkvT = (u16*)(ws + 43122944);
  u16*   kA    = wqkvT;
  u16*   qkv   = (u16*)(ws + 68288768);
  u16*   ctx   = qkv;

  detect_dtype_k<<<1, 256, 0, stream>>>(x, flag);
  convert_any_k<<<8192, 256, 0, stream>>>(x, x_bf, flag);
  transpose_any<<<dim3(96, 32), 256, 0, stream>>>(qkv_w, wqkvT, 2048, 6144, flag);
  transpose_any<<<dim3(32, 32), 256, 0, stream>>>(dense_w, wdT, 2048, 2048, flag);
  rope_table_k<<<512, 256, 0, stream>>>(tab);
  build_bias_k<<<128, 256, 0, stream>>>(rtable, bias, flag);
  // QKV: 256^2 tiles (best measured: 113us) -- 128x256 regressed here (r7)
  gemm256_bt<false><<<dim3(24, 16), 512, 0, stream>>>(x_bf, wqkvT, qkv, 4096, 6144, 2048);
  reorg_k<<<dim3(32, 32), 256, 0, stream>>>(qkv, tab, qA, kA, vT);
  attn_k<<<dim3(16, 32), 256, 0, stream>>>(qA, kA, vT, bias, ctx);
  // out-proj: 128x256 tiles, 8x32 = 256 blocks = 1 exact round
  gemm128_bt<true><<<dim3(8, 32), 512, 0, stream>>>(ctx, wdT, d_out, 4096, 2048, 2048);
}